// Round 2
// baseline (377.947 us; speedup 1.0000x reference)
//
#include <hip/hip_runtime.h>

// Walsh-Hadamard, N = 2^25 fp32, two passes.
// pass1: bits e[13:0] inside contiguous 2^14-float tiles (256 thr, 32 KiB LDS,
//        two 2-round exchanges, compile-time slot indices, v/u ping-pong).
// pass2: bits e[24:14] = rows of a (2048 x 2^14) view (1024 thr, 64 KiB LDS,
//        one all-active hazard-free exchange + 3 shfl_xor stages).

__device__ __forceinline__ void bfly(float4& a, float4& b) {
  float ax = a.x, ay = a.y, az = a.z, aw = a.w;
  a.x = ax + b.x; a.y = ay + b.y; a.z = az + b.z; a.w = aw + b.w;
  b.x = ax - b.x; b.y = ay - b.y; b.z = az - b.z; b.w = aw - b.w;
}

__device__ __forceinline__ void cross4(float4 (&v)[16]) {
#pragma unroll
  for (int m = 0; m < 4; ++m)
#pragma unroll
    for (int k = 0; k < 16; ++k)
      if (!(k & (1 << m))) bfly(v[k], v[k | (1 << m)]);
}

// f4-granular LDS bank swizzle: makes every verified access pattern hit 8
// distinct bank-quads per 8-lane beat (checked per-pattern for pass1).
__device__ __forceinline__ int sw1(int q) { return q ^ (((q >> 4) ^ (q >> 3)) & 7); }

// ---------------- pass 1: e[13:0] ----------------
// Load layout: thread t = F[7:0], regs k = F[11:8]  (F = float4 index in tile).
// exA (phi = F9): regs -> F[3:0];  exB (phi = F3): regs -> F[7:4].
__global__ __launch_bounds__(256, 4) void wht_pass1(const float4* __restrict__ in4,
                                                    float4* __restrict__ out4) {
  __shared__ float4 lds[2048];  // 32 KiB
  const int t = threadIdx.x;
  const int base4 = (int)blockIdx.x << 12;
  const int t3 = (t >> 3) & 1, t54 = (t >> 4) & 3, t6 = (t >> 6) & 1, t7 = (t >> 7) & 1;
  float4 v[16], u[16];
#pragma unroll
  for (int k = 0; k < 16; ++k) v[k] = in4[base4 + t + (k << 8)];
  // e[1:0] inside each float4
#pragma unroll
  for (int k = 0; k < 16; ++k) {
    float4 a = v[k];
    float s0 = a.x + a.y, d0 = a.x - a.y, s1 = a.z + a.w, d1 = a.z - a.w;
    v[k].x = s0 + s1; v[k].y = d0 + d1; v[k].z = s0 - s1; v[k].w = d0 - d1;
  }
  cross4(v);  // e[13:10]

  // exchange A: round j holds F-set {F9 == j}; idx = F[7:0] | F8<<8 | F[11:10]<<9
#pragma unroll
  for (int j = 0; j < 2; ++j) {
    __syncthreads();
#pragma unroll
    for (int a = 0; a < 4; ++a)
#pragma unroll
      for (int b = 0; b < 2; ++b)
        lds[sw1(t | (b << 8) | (a << 9))] = v[b | (j << 1) | (a << 2)];
    __syncthreads();
    if (t7 == j) {  // reader: F[6:4]=t[2:0], F7=t6, F8=t3, F9=t7, F[11:10]=t[5:4]
      const int rb = ((t & 7) << 4) | (t6 << 7) | (t3 << 8) | (t54 << 9);
#pragma unroll
      for (int k = 0; k < 16; ++k) u[k] = lds[sw1(rb | k)];
    }
  }
  cross4(u);  // e[5:2]

  // exchange B: round j holds {F3 == j}; idx = F[2:0] | F[7:4]<<3 | F8<<7 | F9<<8 | F[11:10]<<9
#pragma unroll
  for (int j = 0; j < 2; ++j) {
    __syncthreads();
    {
      const int wb = ((t & 7) << 3) | (t6 << 6) | (t3 << 7) | (t7 << 8) | (t54 << 9);
#pragma unroll
      for (int m = 0; m < 8; ++m) lds[sw1(wb | m)] = u[(j << 3) | m];
    }
    __syncthreads();
    if (t6 == j) {  // reader: F[2:0]=t[2:0], F3=t6, F8=t3, F9=t7, F[11:10]=t[5:4]
      const int rb = (t & 7) | (t3 << 7) | (t7 << 8) | (t54 << 9);
#pragma unroll
      for (int k = 0; k < 16; ++k) v[k] = lds[sw1(rb | (k << 3))];
    }
  }
  cross4(v);  // e[9:6]

  const int sb = (t & 7) | (t6 << 3) | (t3 << 8) | (t7 << 9) | (t54 << 10);
#pragma unroll
  for (int k = 0; k < 16; ++k) out4[base4 + (sb | (k << 4))] = v[k];
}

// ---------------- pass 2: e[24:14] (rows r[10:0], row pitch 2^12 float4) ----
// thread: c = t&7 (col f4), lam = (t>>3)&7 = r[6:4], w = t>>6 = r[3:0] (load)
// regs k = r[10:7]. After exchange: regs = r[3:0], wave = r[10:7].
__device__ __forceinline__ void shfl_bfly(float4 (&v)[16], const int mask) {
  const float s = (threadIdx.x & mask) ? -1.f : 1.f;
#pragma unroll
  for (int k = 0; k < 16; ++k) {
    float4 p;
    p.x = __shfl_xor(v[k].x, mask, 64);
    p.y = __shfl_xor(v[k].y, mask, 64);
    p.z = __shfl_xor(v[k].z, mask, 64);
    p.w = __shfl_xor(v[k].w, mask, 64);
    v[k].x = fmaf(s, v[k].x, p.x);
    v[k].y = fmaf(s, v[k].y, p.y);
    v[k].z = fmaf(s, v[k].z, p.z);
    v[k].w = fmaf(s, v[k].w, p.w);
  }
}

__global__ __launch_bounds__(1024) void wht_pass2(float4* __restrict__ b4) {
  __shared__ float4 lds[4096];  // 64 KiB
  const int t = threadIdx.x;
  const int cb4 = (int)blockIdx.x << 3;
  const int c = t & 7, lam = (t >> 3) & 7, w = t >> 6;
  float4 v[16];
#pragma unroll
  for (int k = 0; k < 16; ++k) {
    const int r = w | (lam << 4) | (k << 7);
    v[k] = b4[(r << 12) | cb4 | c];
  }
  cross4(v);         // e[24:21]  (r[10:7])
  shfl_bfly(v, 8);   // e[18] (r4)
  shfl_bfly(v, 16);  // e[19] (r5)
  shfl_bfly(v, 32);  // e[20] (r6)

  // exchange: phi = (r7^r0, r8^r1); 4 rounds, group q = j ^ (w&3), all-active,
  // write-group == read-group -> hazard-free. idx = c | r[3:0]<<3 | r[6:4]<<7 | r[10:9]<<10
  const int wq = w & 3;
  const int ibase = c | (w << 3) | (lam << 7);
  const int rbase = c | (lam << 7) | ((w >> 2) << 10);
#pragma unroll
  for (int j = 0; j < 4; ++j) {
    const int q = j ^ wq;
    __syncthreads();
#pragma unroll
    for (int Q = 0; Q < 4; ++Q)
      if (q == Q) {
#pragma unroll
        for (int s = 0; s < 4; ++s) lds[ibase | (s << 10)] = v[Q | (s << 2)];
      }
    __syncthreads();
#pragma unroll
    for (int Q = 0; Q < 4; ++Q)
      if (q == Q) {
#pragma unroll
        for (int s = 0; s < 4; ++s)
          v[Q | (s << 2)] = lds[rbase | ((Q | (s << 2)) << 3)];
      }
  }
  cross4(v);  // e[17:14]  (r[3:0])

#pragma unroll
  for (int k = 0; k < 16; ++k) {
    const int r = k | (lam << 4) | (w << 7);
    b4[(r << 12) | cb4 | c] = v[k];
  }
}

extern "C" void kernel_launch(void* const* d_in, const int* in_sizes, int n_in,
                              void* d_out, int out_size, void* d_ws, size_t ws_size,
                              hipStream_t stream) {
  (void)in_sizes; (void)n_in; (void)d_ws; (void)ws_size; (void)out_size;
  const float* x = (const float*)d_in[0];
  float* out = (float*)d_out;
  wht_pass1<<<2048, 256, 0, stream>>>((const float4*)x, (float4*)out);
  wht_pass2<<<512, 1024, 0, stream>>>((float4*)out);
}

// Round 3
// 307.545 us; speedup vs baseline: 1.2289x; 1.2289x over previous
//
#include <hip/hip_runtime.h>

// Walsh-Hadamard, N = 2^25 fp32, two passes.
// pass1: e[13:0] in contiguous 2^14-float tiles. 256 thr x 16 float4, 32 KiB
//        LDS. Exchanges run in 2 rounds selected by reg bit k3 (=F11, never
//        swapped): round j moves regs {k3==j} (compile-time indices), all
//        lanes active, in-place (no second array -> no spills).
// pass2: e[24:14] = rows of a (2048 x 2^12-float4) view. 512 thr x 16 float4,
//        4-f4 column slab (64 B sector chunks), 64 KiB LDS, same exchange
//        structure (selector k3 = r10).

__device__ __forceinline__ void bfly(float4& a, float4& b) {
  float ax = a.x, ay = a.y, az = a.z, aw = a.w;
  a.x = ax + b.x; a.y = ay + b.y; a.z = az + b.z; a.w = aw + b.w;
  b.x = ax - b.x; b.y = ay - b.y; b.z = az - b.z; b.w = aw - b.w;
}

__device__ __forceinline__ void crossbit(float4 (&v)[16], const int bit) {
#pragma unroll
  for (int k = 0; k < 16; ++k)
    if (!(k & bit)) bfly(v[k], v[k | bit]);
}

// ---------------- pass 1 ----------------
// F = float4 index in tile (12 bits). e[1:0] in-f4, e[13:2] = F[11:0].
// L0: t=F[7:0], k=F[11:8].  X1: k[2:0]<->t[2:0]. X2: k[2:0]<->t[5:3].
// X3: k[1:0]<->t[7:6].  LDS key = F[10:0] (F11 = round), swizzle ^((A>>8)&7).
__global__ __launch_bounds__(256) void wht_pass1(const float4* __restrict__ in4,
                                                 float4* __restrict__ out4) {
  __shared__ float4 lds[2048];  // 32 KiB
  const int t = threadIdx.x;
  const int base4 = (int)blockIdx.x << 12;
  const int t7l = t & 7, thi = t & 0xF8;
  const int t53 = (t >> 3) & 7, t76 = (t >> 6) & 3;
  float4 v[16];
#pragma unroll
  for (int k = 0; k < 16; ++k) v[k] = in4[base4 + t + (k << 8)];
  // e[1:0] inside each float4
#pragma unroll
  for (int k = 0; k < 16; ++k) {
    float4 a = v[k];
    float s0 = a.x + a.y, d0 = a.x - a.y, s1 = a.z + a.w, d1 = a.z - a.w;
    v[k] = make_float4(s0 + s1, d0 + d1, s0 - s1, d0 - d1);
  }
  crossbit(v, 1); crossbit(v, 2); crossbit(v, 4); crossbit(v, 8);  // e[13:10]

  const int br1 = thi | (t7l << 8) | t7l;               // ^m per access
  const int br2 = (t53 ^ t7l) | (t76 << 6) | (t7l << 8);  // | (m<<3)
  const int br3 = (t53 ^ t7l) | (t76 << 3) | (t7l << 8);  // | m-bits{5,6,7}

  // X1: regs -> F[2:0]
#pragma unroll
  for (int j = 0; j < 2; ++j) {
    __syncthreads();
#pragma unroll
    for (int m = 0; m < 8; ++m) lds[(t ^ m) | (m << 8)] = v[(j << 3) | m];
    __syncthreads();
#pragma unroll
    for (int m = 0; m < 8; ++m) v[(j << 3) | m] = lds[br1 ^ m];
  }
  crossbit(v, 1); crossbit(v, 2); crossbit(v, 4);  // e[4:2]

  // X2: regs -> F[5:3]
#pragma unroll
  for (int j = 0; j < 2; ++j) {
    __syncthreads();
#pragma unroll
    for (int m = 0; m < 8; ++m) lds[br1 ^ m] = v[(j << 3) | m];
    __syncthreads();
#pragma unroll
    for (int m = 0; m < 8; ++m) v[(j << 3) | m] = lds[br2 | (m << 3)];
  }
  crossbit(v, 1); crossbit(v, 2); crossbit(v, 4);  // e[7:5]

  // X3: regs k[1:0] -> F[7:6] (k2 keeps F5)
#pragma unroll
  for (int j = 0; j < 2; ++j) {
    __syncthreads();
#pragma unroll
    for (int m = 0; m < 8; ++m) lds[br2 | (m << 3)] = v[(j << 3) | m];
    __syncthreads();
#pragma unroll
    for (int m = 0; m < 8; ++m)
      v[(j << 3) | m] =
          lds[br3 | (((m >> 2) & 1) << 5) | ((m & 1) << 6) | (((m >> 1) & 1) << 7)];
  }
  crossbit(v, 1); crossbit(v, 2);  // e[9:8]

  // store: F[2:0]=t53, F[4:3]=t76, F5=k2, F6=k0, F7=k1, F[10:8]=t[2:0], F11=k3
  const int Fb = t53 | (t76 << 3) | (t7l << 8);
#pragma unroll
  for (int k = 0; k < 16; ++k) {
    const int F = Fb | (((k >> 2) & 1) << 5) | ((k & 1) << 6) |
                  (((k >> 1) & 1) << 7) | (((k >> 3) & 1) << 11);
    out4[base4 + F] = v[k];
  }
}

// ---------------- pass 2 ----------------
// rows r[10:0] (pitch 2^12 f4), block owns 4 f4-cols. L0: t[1:0]=c,
// t[5:2]=r[3:0], t[8:6]=r[6:4], k[2:0]=r[9:7], k3=r10.
// X1: k[2:0]<->t[4:2](r[2:0]). X2: k[2:0]<->t{5,6,7}(r[5:3]). X3: k0<->t8(r6).
// LDS key A = c | r[9:0]<<2 (4096 slots), swizzle ^((A>>9)&7).
__global__ __launch_bounds__(512) void wht_pass2(float4* __restrict__ b4) {
  __shared__ float4 lds[4096];  // 64 KiB
  const int t = threadIdx.x;
  const int cb4 = (int)blockIdx.x << 2;
  const int c = t & 3;
  const int t42 = (t >> 2) & 7;
  const int gb = cb4 | c;
  const int rl = ((t >> 2) & 15) | (((t >> 6) & 7) << 4);
  float4 v[16];
#pragma unroll
  for (int j = 0; j < 2; ++j)
#pragma unroll
    for (int m = 0; m < 8; ++m)
      v[(j << 3) | m] = b4[((rl | (m << 7) | (j << 10)) << 12) | gb];
  crossbit(v, 1); crossbit(v, 2); crossbit(v, 4); crossbit(v, 8);  // e[24:21]

  const int EX = (((t & 0x1E3) | (t42 << 9)) ^ t42);  // ^(m<<2) per access
  const int G = (((t & 3) | (((t >> 5) & 1) << 2) | (((t >> 6) & 1) << 3) |
                  (((t >> 7) & 1) << 4) | (((t >> 8) & 1) << 8) | (t42 << 9)) ^ t42);
  const int H = (((t & 3) | (((t >> 5) & 1) << 2) | (((t >> 6) & 1) << 3) |
                  (((t >> 7) & 1) << 4) | (((t >> 8) & 1) << 5) | (t42 << 9)) ^ t42);

  // X1: regs -> r[2:0]
#pragma unroll
  for (int j = 0; j < 2; ++j) {
    __syncthreads();
#pragma unroll
    for (int m = 0; m < 8; ++m) lds[(t ^ m) | (m << 9)] = v[(j << 3) | m];
    __syncthreads();
#pragma unroll
    for (int m = 0; m < 8; ++m) v[(j << 3) | m] = lds[EX ^ (m << 2)];
  }
  crossbit(v, 1); crossbit(v, 2); crossbit(v, 4);  // e[16:14]

  // X2: regs -> r[5:3]
#pragma unroll
  for (int j = 0; j < 2; ++j) {
    __syncthreads();
#pragma unroll
    for (int m = 0; m < 8; ++m) lds[EX ^ (m << 2)] = v[(j << 3) | m];
    __syncthreads();
#pragma unroll
    for (int m = 0; m < 8; ++m) v[(j << 3) | m] = lds[G | (m << 5)];
  }
  crossbit(v, 1); crossbit(v, 2); crossbit(v, 4);  // e[19:17]

  // X3: reg k0 -> r6
#pragma unroll
  for (int j = 0; j < 2; ++j) {
    __syncthreads();
#pragma unroll
    for (int m = 0; m < 8; ++m) lds[G | (m << 5)] = v[(j << 3) | m];
    __syncthreads();
#pragma unroll
    for (int m = 0; m < 8; ++m)
      v[(j << 3) | m] =
          lds[H | (((m >> 1) & 1) << 6) | (((m >> 2) & 1) << 7) | ((m & 1) << 8)];
  }
  crossbit(v, 1);  // e[20]

  // store: r0..r3 = t5,t6,t7,t8; r4=k1, r5=k2, r6=k0, r[9:7]=t[4:2], r10=k3
  const int rs = ((t >> 5) & 1) | (((t >> 6) & 1) << 1) | (((t >> 7) & 1) << 2) |
                 (((t >> 8) & 1) << 3) | (t42 << 7);
#pragma unroll
  for (int k = 0; k < 16; ++k) {
    const int r = rs | (((k >> 1) & 1) << 4) | (((k >> 2) & 1) << 5) |
                  ((k & 1) << 6) | (((k >> 3) & 1) << 10);
    b4[(r << 12) | gb] = v[k];
  }
}

extern "C" void kernel_launch(void* const* d_in, const int* in_sizes, int n_in,
                              void* d_out, int out_size, void* d_ws, size_t ws_size,
                              hipStream_t stream) {
  (void)in_sizes; (void)n_in; (void)d_ws; (void)ws_size; (void)out_size;
  const float* x = (const float*)d_in[0];
  float* out = (float*)d_out;
  wht_pass1<<<2048, 256, 0, stream>>>((const float4*)x, (float4*)out);
  wht_pass2<<<1024, 512, 0, stream>>>((float4*)out);
}